// Round 8
// baseline (258.890 us; speedup 1.0000x reference)
//
#include <hip/hip_runtime.h>
#include <hip/hip_bf16.h>

#define FEATS 1024
#define NH 16
#define HD 64
#define SEQ 2048
#define BATCH 2
#define MTOT (BATCH*SEQ)   // 4096
#define MLPH 4096
// log2(e)/sqrt(FEATS): folded into wq/bq so attn uses exp2f(s) directly
#define QSCALE 0.04508422277369218f

typedef __attribute__((ext_vector_type(8))) short bf16x8;   // 8 bf16 (4 VGPRs)
typedef __attribute__((ext_vector_type(4))) short bf16x4;   // 4 bf16 (2 VGPRs)
typedef __attribute__((ext_vector_type(4))) float f32x4;

static_assert(sizeof(bf16x8) == 16, "bf16x8 must be 16B");

__device__ __forceinline__ unsigned short f2bf(float f) {
    unsigned int u = __float_as_uint(f);
    unsigned int lsb = (u >> 16) & 1u;
    u += 0x7fffu + lsb;              // round-to-nearest-even
    return (unsigned short)(u >> 16);
}

// async global->LDS, 16B per lane. Dest must be wave-uniform base + lane*16.
#define ASYNC16(GP, LP) __builtin_amdgcn_global_load_lds( \
    (const __attribute__((address_space(1))) void*)(GP),  \
    (__attribute__((address_space(3))) void*)(LP), 16, 0, 0)

// ---------------------------------------------------------------- converts
__global__ __launch_bounds__(256) void cvt_kernel(const float* __restrict__ src,
                                                  unsigned short* __restrict__ dst,
                                                  int n, float scale) {
    int i = (blockIdx.x * 256 + threadIdx.x) * 4;
    if (i + 3 < n) {
        float4 v = *(const float4*)(src + i);
        ushort4 o;
        o.x = f2bf(v.x * scale); o.y = f2bf(v.y * scale);
        o.z = f2bf(v.z * scale); o.w = f2bf(v.w * scale);
        *(ushort4*)(dst + i) = o;
    }
}

__global__ __launch_bounds__(256) void concat3_kernel(const float* __restrict__ a,
                                                      const float* __restrict__ b,
                                                      const float* __restrict__ c,
                                                      float* __restrict__ o) {
    int i = blockIdx.x * 256 + threadIdx.x;   // 3072 total
    float v = (i < 1024) ? a[i] * QSCALE : ((i < 2048) ? b[i - 1024] : c[i - 2048]);
    o[i] = v;
}

// ---------------------------------------------------------------- layernorm
__global__ __launch_bounds__(256) void ln_kernel(const float* __restrict__ x,
                                                 const float* __restrict__ g,
                                                 const float* __restrict__ bta,
                                                 unsigned short* __restrict__ h) {
    __shared__ float red[8];
    const int row = blockIdx.x;
    const int t = threadIdx.x;
    const float* xr = x + (size_t)row * FEATS;
    float4 v = ((const float4*)xr)[t];
    float s  = v.x + v.y + v.z + v.w;
    float ss = v.x * v.x + v.y * v.y + v.z * v.z + v.w * v.w;
#pragma unroll
    for (int off = 1; off < 64; off <<= 1) {
        s  += __shfl_xor(s, off);
        ss += __shfl_xor(ss, off);
    }
    const int w = t >> 6;
    if ((t & 63) == 0) { red[w] = s; red[4 + w] = ss; }
    __syncthreads();
    s  = red[0] + red[1] + red[2] + red[3];
    ss = red[4] + red[5] + red[6] + red[7];
    const float mu  = s * (1.f / FEATS);
    const float var = ss * (1.f / FEATS) - mu * mu;
    const float rs  = rsqrtf(var + 1e-5f);
    float4 gv = ((const float4*)g)[t];
    float4 bv = ((const float4*)bta)[t];
    ushort4 ov;
    ov.x = f2bf((v.x - mu) * rs * gv.x + bv.x);
    ov.y = f2bf((v.y - mu) * rs * gv.y + bv.y);
    ov.z = f2bf((v.z - mu) * rs * gv.z + bv.z);
    ov.w = f2bf((v.w - mu) * rs * gv.w + bv.w);
    ((ushort4*)h)[(size_t)row * (FEATS / 4) + t] = ov;
}

// ---------------------------------------------------------------- GEMM
// C[M,N] = epilogue(A[M,K] @ W[N,K]^T + bias); BMx128 tile (BM = MW*32),
// BK=32. Depth-2 pipeline: 3 LDS buffers, counted vmcnt, raw s_barrier.
// MW=4: 128x128, 4 loads/stage, 3 blocks/CU. MW=2: 64x128, 3 loads/stage,
// 4 blocks/CU (for N=1024 GEMMs whose grid would otherwise be 1 block/CU).
template <int MW, bool RELU, bool ADD, bool OUTBF16>
__global__ __launch_bounds__(256, (MW == 4 ? 3 : 4))
void gemm_kernel(const unsigned short* __restrict__ A,
                 const unsigned short* __restrict__ W,
                 const float* __restrict__ bias,
                 const float* __restrict__ addend,
                 void* __restrict__ outp,
                 int M, int N, int K, int gx) {
    constexpr int BM = MW * 32;
    __shared__ unsigned short ldsA[3][BM * 32];
    __shared__ unsigned short ldsB[3][128 * 32];

    const int t = threadIdx.x;
    const int w = t >> 6, lane = t & 63;
    const int wr = w >> 1, wc = w & 1;
    const int li = lane & 15, lj = lane >> 4;

    const int nwg = gridDim.x;
    const int cpx = nwg >> 3;
    const int wg = blockIdx.x;
    const int swz = (wg & 7) * cpx + (wg >> 3);
    const int mb = (swz / gx) * BM, nb = (swz % gx) * 128;

    const int srow = lane >> 2, sc = (lane & 3) * 8;
    const unsigned short* gA = A + (size_t)(mb + w * 16 + srow) * K + sc;
    const unsigned short* gB = W + (size_t)(nb + w * 16 + srow) * K + sc;
    const size_t half = (size_t)64 * K;
    const int lbase = w * 512 + lane * 8;

    const int nt = K >> 5;

#define STAGE(BUF, K0)                                             \
    do {                                                           \
        unsigned short* la_ = &ldsA[BUF][lbase];                   \
        unsigned short* lb_ = &ldsB[BUF][lbase];                   \
        ASYNC16(gA + (K0), la_);                                   \
        if constexpr (MW == 4) ASYNC16(gA + half + (K0), la_ + 2048); \
        ASYNC16(gB + (K0), lb_);                                   \
        ASYNC16(gB + half + (K0), lb_ + 2048);                     \
    } while (0)

#define WAITN()                                                     \
    do {                                                            \
        if constexpr (MW == 4) asm volatile("s_waitcnt vmcnt(4)" ::: "memory"); \
        else                   asm volatile("s_waitcnt vmcnt(3)" ::: "memory"); \
    } while (0)

    STAGE(0, 0);
    STAGE(1, 32);
    WAITN();
    __builtin_amdgcn_s_barrier();

    f32x4 acc[MW][4] = {};

    for (int i = 0; i < nt; ++i) {
        const int cur = i % 3;
        const unsigned short* Al = &ldsA[cur][0];
        const unsigned short* Bl = &ldsB[cur][0];

        bf16x8 af[MW], bfr[4];
#pragma unroll
        for (int m = 0; m < MW; m++)
            af[m] = *(const bf16x8*)(Al + (wr * (BM / 2) + m * 16 + li) * 32 + lj * 8);
#pragma unroll
        for (int n = 0; n < 4; n++)
            bfr[n] = *(const bf16x8*)(Bl + (wc * 64 + n * 16 + li) * 32 + lj * 8);

        const int pf = i + 2 < nt;
        if (pf) STAGE((i + 2) % 3, (i + 2) * 32);

#pragma unroll
        for (int m = 0; m < MW; m++)
#pragma unroll
            for (int n = 0; n < 4; n++)
                acc[m][n] = __builtin_amdgcn_mfma_f32_16x16x32_bf16(af[m], bfr[n], acc[m][n], 0, 0, 0);

        if (i + 1 < nt) {
            if (pf) WAITN();
            else    asm volatile("s_waitcnt vmcnt(0)" ::: "memory");
            __builtin_amdgcn_s_barrier();
        }
    }
#undef STAGE
#undef WAITN

#pragma unroll
    for (int m = 0; m < MW; m++) {
#pragma unroll
        for (int n = 0; n < 4; n++) {
            const int col = nb + wc * 64 + n * 16 + li;
            const float bv = bias[col];
#pragma unroll
            for (int r = 0; r < 4; r++) {
                const int row = mb + wr * (BM / 2) + m * 16 + lj * 4 + r;
                float v = acc[m][n][r] + bv;
                if (RELU) v = fmaxf(v, 0.f);
                if (ADD)  v += addend[(size_t)row * N + col];
                if (OUTBF16)
                    ((unsigned short*)outp)[(size_t)row * N + col] = f2bf(v);
                else
                    ((float*)outp)[(size_t)row * N + col] = v;
            }
        }
    }
}

// ---------------------------------------------------------------- V transpose
__global__ __launch_bounds__(256) void vtrans_kernel(const unsigned short* __restrict__ qkv,
                                                     unsigned short* __restrict__ vt) {
    constexpr int LDV = 68;
    __shared__ unsigned short Vl[64 * LDV];
    const int bh = blockIdx.x, st = blockIdx.y;
    const int b = bh >> 4, h = bh & 15;
    const int t = threadIdx.x;
    const unsigned short* src = qkv + (size_t)(b * SEQ + st * 64) * (3 * FEATS) + 2 * FEATS + h * HD;
#pragma unroll
    for (int i = 0; i < 2; i++) {
        int idx = t + i * 256;
        int r = idx >> 3, c = (idx & 7) * 8;
        *(bf16x8*)(Vl + r * LDV + c) = *(const bf16x8*)(src + (size_t)r * (3 * FEATS) + c);
    }
    __syncthreads();
    unsigned short* dst = vt + (size_t)bh * HD * SEQ + st * 64;
#pragma unroll
    for (int i = 0; i < 2; i++) {
        int idx = t + i * 256;
        int d = idx >> 3, s8 = (idx & 7) * 8;
        bf16x8 v;
#pragma unroll
        for (int j = 0; j < 8; j++) v[j] = Vl[(s8 + j) * LDV + d];
        *(bf16x8*)(dst + (size_t)d * SEQ + s8) = v;
    }
}

// ---------------------------------------------------------------- attention
// 512 thr (8 waves x 16 q-rows), KV tile 128. Swapped QK^T keeps P
// lane-local; cvt_pk packs PV A-frags in-register. Q pre-scaled (exp2f(s)
// direct). Grid: bh on x so the 16 q-tile blocks of a head share an XCD L2
// (wgid = bh + 32*qtile -> xcd = bh%8; 2MB K/V per XCD).
__global__ __launch_bounds__(512, 4)
void attn_kernel(const unsigned short* __restrict__ qkv,
                 const unsigned short* __restrict__ vt,
                 unsigned short* __restrict__ out) {
    constexpr int LK = 72;    // K rows: 64 d + pad (shorts)
    constexpr int LV = 136;   // V^T rows: 128 keys + pad (shorts)
    __shared__ unsigned short Kl[2][128 * LK];
    __shared__ unsigned short Vtl[2][64 * LV];

    const int bh = blockIdx.x;
    const int b = bh >> 4, h = bh & 15;
    const int q0 = blockIdx.y * 128;
    const int t = threadIdx.x, w = t >> 6, lane = t & 63;
    const int li = lane & 15, lj = lane >> 4;

    const size_t rstr = 3 * FEATS;
    const unsigned short* qkvb = qkv + (size_t)(b * SEQ) * rstr;
    const unsigned short* ksrc = qkvb + FEATS + h * HD;
    const unsigned short* vsrc = vt + (size_t)bh * HD * SEQ;

    // Q fragments in registers: B-operand of S^T = K Q^T
    bf16x8 aq[2];
#pragma unroll
    for (int kk = 0; kk < 2; kk++)
        aq[kk] = *(const bf16x8*)(qkvb + (size_t)(q0 + w * 16 + li) * rstr + h * HD + kk * 32 + lj * 8);

    f32x4 o[4] = {};
    float lsum = 0.f;   // denominator for q = li

    // K staging: thread t -> key = t>>2, d-chunk (t&3)*16; two b128
    const int skey = t >> 2, sc = (t & 3) * 16;
    const unsigned short* kg = ksrc + (size_t)skey * rstr + sc;
    const int ldoK = skey * LK + sc;
    // V staging: thread t -> d = t>>3, key-chunk c0 = (t&7)*16; two b128 ->
    // four b64 at permuted slots: pos(k)=(k&96)|(((k>>2)&3)<<3)|(((k>>4)&1)<<2)|(k&3)
    const int sd = t >> 3, c0 = (t & 7) * 16;
    const unsigned short* vg = vsrc + (size_t)sd * SEQ + c0;
    const int posA = (c0 & 96) | (((c0 >> 2) & 3) << 3) | (((c0 >> 4) & 1) << 2);
    const int ldoV = sd * LV + posA;

    const int nt = SEQ / 128;   // 16

#define VSPLIT(VR0, VR1, BUF)                                            \
    do {                                                                 \
        *(bf16x4*)(&Vtl[BUF][ldoV])      = __builtin_shufflevector(VR0, VR0, 0, 1, 2, 3); \
        *(bf16x4*)(&Vtl[BUF][ldoV + 8])  = __builtin_shufflevector(VR0, VR0, 4, 5, 6, 7); \
        *(bf16x4*)(&Vtl[BUF][ldoV + 16]) = __builtin_shufflevector(VR1, VR1, 0, 1, 2, 3); \
        *(bf16x4*)(&Vtl[BUF][ldoV + 24]) = __builtin_shufflevector(VR1, VR1, 4, 5, 6, 7); \
    } while (0)

    // prologue: tile 0 staged
    {
        bf16x8 k0 = *(const bf16x8*)kg;
        bf16x8 k1 = *(const bf16x8*)(kg + 8);
        bf16x8 v0 = *(const bf16x8*)vg;
        bf16x8 v1 = *(const bf16x8*)(vg + 8);
        *(bf16x8*)(&Kl[0][ldoK])     = k0;
        *(bf16x8*)(&Kl[0][ldoK + 8]) = k1;
        VSPLIT(v0, v1, 0);
    }

    int cur = 0;
    for (int i = 0; i < nt; ++i) {
        // issue next tile's global loads early (hidden under this tile's compute)
        bf16x8 kr0, kr1, vr0, vr1;
        if (i + 1 < nt) {
            const unsigned short* kn = kg + (size_t)(i + 1) * 128 * rstr;
            const unsigned short* vn = vg + (i + 1) * 128;
            kr0 = *(const bf16x8*)kn;
            kr1 = *(const bf16x8*)(kn + 8);
            vr0 = *(const bf16x8*)vn;
            vr1 = *(const bf16x8*)(vn + 8);
        }

        // barrier: LDS writes of buf[cur] visible; global loads stay in flight
        asm volatile("s_waitcnt lgkmcnt(0)" ::: "memory");
        __builtin_amdgcn_s_barrier();

        const unsigned short* Kc = Kl[cur];
        const unsigned short* Vc = Vtl[cur];

        // ---- S^T = K Q^T : lane holds S[q=li][key = n*16 + lj*4 + r] ----
        f32x4 s[8];
        __builtin_amdgcn_s_setprio(1);
#pragma unroll
        for (int n = 0; n < 8; n++) {
            bf16x8 k0 = *(const bf16x8*)(Kc + (n * 16 + li) * LK + lj * 8);
            bf16x8 k1 = *(const bf16x8*)(Kc + (n * 16 + li) * LK + 32 + lj * 8);
            f32x4 acc = {};
            acc = __builtin_amdgcn_mfma_f32_16x16x32_bf16(k0, aq[0], acc, 0, 0, 0);
            acc = __builtin_amdgcn_mfma_f32_16x16x32_bf16(k1, aq[1], acc, 0, 0, 0);
            s[n] = acc;
        }
        __builtin_amdgcn_s_setprio(0);

        // ---- p = exp2(s) (pre-scaled); pack PV A-frags in-register ----
        bf16x8 A[4];
#pragma unroll
        for (int kk = 0; kk < 4; kk++) {
            float p[8];
#pragma unroll
            for (int r = 0; r < 4; r++) {
                p[r]     = exp2f(s[2 * kk][r]);
                p[4 + r] = exp2f(s[2 * kk + 1][r]);
                lsum += p[r] + p[4 + r];
            }
            union { unsigned u[4]; bf16x8 v; } Au;
            asm("v_cvt_pk_bf16_f32 %0, %1, %2" : "=v"(Au.u[0]) : "v"(p[0]), "v"(p[1]));
            asm("v_cvt_pk_bf16_f32 %0, %1, %2" : "=v"(Au.u[1]) : "v"(p[2]), "v"(p[3]));
            asm("v_cvt_pk_bf16_f32 %0, %1, %2" : "=v"(Au.u[2]) : "v"(p[4]), "v"(p[5]));
            asm("v_cvt_pk_bf16_f32 %0, %1, %2" : "=v"(Au.u[3]) : "v"(p[6]), "v"(p[7]));
            A[kk] = Au.v;
        }

        // ---- O += P V (V^T rows key-slot-permuted to match A) ----
        __builtin_amdgcn_s_setprio(1);
#pragma unroll
        for (int n = 0; n < 4; n++) {
#pragma unroll
            for (int kk = 0; kk < 4; kk++) {
                bf16x8 bv = *(const bf16x8*)(Vc + (n * 16 + li) * LV + kk * 32 + lj * 8);
                o[n] = __builtin_amdgcn_mfma_f32_16x16x32_bf16(A[kk], bv, o[n], 0, 0, 0);
            }
        }
        __builtin_amdgcn_s_setprio(0);

        // write-late: prefetched tile into the other buffer
        if (i + 1 < nt) {
            *(bf16x8*)(&Kl[cur ^ 1][ldoK])     = kr0;
            *(bf16x8*)(&Kl[cur ^ 1][ldoK + 8]) = kr1;
            VSPLIT(vr0, vr1, cur ^ 1);
        }
        cur ^= 1;
    }
#undef VSPLIT

    // denominator: full sum for q = li lives across lj groups
    lsum += __shfl_xor(lsum, 16);
    lsum += __shfl_xor(lsum, 32);
    const float dinv = 1.f / lsum;
    // epilogue rows are q' = lj*4 + r -> fetch that q's inv via lane shuffle
    float inv[4];
#pragma unroll
    for (int r = 0; r < 4; r++)
        inv[r] = __shfl(dinv, lj * 4 + r);

    unsigned short* ob = out + (size_t)(b * SEQ + q0 + w * 16) * FEATS + h * HD;
#pragma unroll
    for (int n = 0; n < 4; n++)
#pragma unroll
        for (int r = 0; r < 4; r++)
            ob[(size_t)(lj * 4 + r) * FEATS + n * 16 + li] = f2bf(o[n][r] * inv[r]);
}

// ---------------------------------------------------------------- launch
extern "C" void kernel_launch(void* const* d_in, const int* in_sizes, int n_in,
                              void* d_out, int out_size, void* d_ws, size_t ws_size,
                              hipStream_t stream) {
    const float* x     = (const float*)d_in[0];
    const float* ln1_g = (const float*)d_in[1];
    const float* ln1_b = (const float*)d_in[2];
    const float* wq    = (const float*)d_in[3];
    const float* bq    = (const float*)d_in[4];
    const float* wk    = (const float*)d_in[5];
    const float* bk    = (const float*)d_in[6];
    const float* wv    = (const float*)d_in[7];
    const float* bvv   = (const float*)d_in[8];
    const float* wo    = (const float*)d_in[9];
    const float* bo    = (const float*)d_in[10];
    const float* ln2_g = (const float*)d_in[11];
    const float* ln2_b = (const float*)d_in[12];
    const float* w1    = (const float*)d_in[13];
    const float* b1    = (const float*)d_in[14];
    const float* w2    = (const float*)d_in[15];
    const float* b2    = (const float*)d_in[16];

    // ---- workspace layout (~84 MB) ----
    unsigned short* wqkv_b = (unsigned short*)d_ws;                 // 3072*1024
    unsigned short* wo_b   = wqkv_b + 3072 * 1024;                  // 1024*1024
    unsigned short* w1_b   = wo_b + 1024 * 1024;                    // 4096*1024
    unsigned short* w2_b   = w1_b + 4096 * 1024;                    // 1024*4096
    float*          bqkv   = (float*)(w2_b + 1024 * 4096);          // 3072
    unsigned short* region = (unsigned short*)(bqkv + 3072);
    unsigned short* qkvb   = region;                                // 4096*3072
    unsigned short* hb     = region + (size_t)4096 * 3072;          // 4096*1024 (LN1 out)
    unsigned short* vtb    = hb;                                    // 32*64*2048 (hb dead after QKV gemm)
    unsigned short* a1     = region;                                // 4096*4096 (qkv+vt dead after attn)
    unsigned short* attn_o = region + (size_t)4096 * 4096;          // 4096*1024
    unsigned short* h2     = attn_o;                                // alias (attn_o dead when written)
    float*          out1   = (float*)(attn_o + (size_t)4096 * 1024);// 4096*1024 fp32
    float*          outf   = (float*)d_out;

    dim3 blk(256);

    cvt_kernel<<<1024, blk, 0, stream>>>(wq, wqkv_b, 1024 * 1024, QSCALE);
    cvt_kernel<<<1024, blk, 0, stream>>>(wk, wqkv_b + 1024 * 1024, 1024 * 1024, 1.0f);
    cvt_kernel<<<1024, blk, 0, stream>>>(wv, wqkv_b + 2 * 1024 * 1024, 1024 * 1024, 1.0f);
    cvt_kernel<<<1024, blk, 0, stream>>>(wo, wo_b, 1024 * 1024, 1.0f);
    cvt_kernel<<<4096, blk, 0, stream>>>(w1, w1_b, 4096 * 1024, 1.0f);
    cvt_kernel<<<4096, blk, 0, stream>>>(w2, w2_b, 4096 * 1024, 1.0f);
    concat3_kernel<<<12, blk, 0, stream>>>(bq, bk, bvv, bqkv);

    ln_kernel<<<MTOT, blk, 0, stream>>>(x, ln1_g, ln1_b, hb);

    // fused QKV gemm: (4096,1024) @ (3072,1024)^T ; grid 24x32 = 768 blocks
    gemm_kernel<4, false, false, true><<<768, blk, 0, stream>>>(
        hb, wqkv_b, bqkv, nullptr, qkvb, MTOT, 3072, FEATS, 24);

    vtrans_kernel<<<dim3(BATCH * NH, SEQ / 64), blk, 0, stream>>>(qkvb, vtb);

    attn_kernel<<<dim3(BATCH * NH, SEQ / 128), dim3(512), 0, stream>>>(qkvb, vtb, attn_o);

    // out proj + residual: 64x128 tiles -> grid 8x64 = 512 blocks (2+/CU)
    gemm_kernel<2, false, true, false><<<512, blk, 0, stream>>>(
        attn_o, wo_b, bo, x, out1, MTOT, FEATS, FEATS, 8);

    ln_kernel<<<MTOT, blk, 0, stream>>>(out1, ln2_g, ln2_b, h2);

    // MLP1: grid 32x32 = 1024 blocks
    gemm_kernel<4, true, false, true><<<1024, blk, 0, stream>>>(
        h2, w1_b, b1, nullptr, a1, MTOT, MLPH, FEATS, 32);

    // MLP2: 64x128 tiles -> grid 8x64 = 512 blocks
    gemm_kernel<2, true, true, false><<<512, blk, 0, stream>>>(
        a1, w2_b, b2, out1, outf, MTOT, FEATS, MLPH, 8);
}

// Round 9
// 235.968 us; speedup vs baseline: 1.0971x; 1.0971x over previous
//
#include <hip/hip_runtime.h>
#include <hip/hip_bf16.h>

#define FEATS 1024
#define NH 16
#define HD 64
#define SEQ 2048
#define BATCH 2
#define MTOT (BATCH*SEQ)   // 4096
#define MLPH 4096
// log2(e)/sqrt(FEATS): folded into wq/bq so attn uses exp2f(s) directly
#define QSCALE 0.04508422277369218f

typedef __attribute__((ext_vector_type(8))) short bf16x8;   // 8 bf16 (4 VGPRs)
typedef __attribute__((ext_vector_type(4))) short bf16x4;   // 4 bf16 (2 VGPRs)
typedef __attribute__((ext_vector_type(4))) float f32x4;

static_assert(sizeof(bf16x8) == 16, "bf16x8 must be 16B");

__device__ __forceinline__ unsigned short f2bf(float f) {
    unsigned int u = __float_as_uint(f);
    unsigned int lsb = (u >> 16) & 1u;
    u += 0x7fffu + lsb;              // round-to-nearest-even
    return (unsigned short)(u >> 16);
}

// async global->LDS, 16B per lane. Dest must be wave-uniform base + lane*16.
#define ASYNC16(GP, LP) __builtin_amdgcn_global_load_lds( \
    (const __attribute__((address_space(1))) void*)(GP),  \
    (__attribute__((address_space(3))) void*)(LP), 16, 0, 0)

// ---------------------------------------------------------------- converts
// single launch for all 6 weight matrices (dests are contiguous in ws)
__global__ __launch_bounds__(256) void cvt_all_kernel(
    const float* __restrict__ wq, const float* __restrict__ wk,
    const float* __restrict__ wv, const float* __restrict__ wo,
    const float* __restrict__ w1, const float* __restrict__ w2,
    unsigned short* __restrict__ dst) {
    const size_t i = ((size_t)blockIdx.x * 256 + threadIdx.x) * 4;
    const size_t MB = (size_t)1024 * 1024;
    const float* s;
    size_t off;
    float sc = 1.0f;
    if (i < MB)            { s = wq; off = i;          sc = QSCALE; }
    else if (i < 2 * MB)   { s = wk; off = i - MB; }
    else if (i < 3 * MB)   { s = wv; off = i - 2 * MB; }
    else if (i < 4 * MB)   { s = wo; off = i - 3 * MB; }
    else if (i < 8 * MB)   { s = w1; off = i - 4 * MB; }
    else                   { s = w2; off = i - 8 * MB; }
    float4 v = *(const float4*)(s + off);
    ushort4 o;
    o.x = f2bf(v.x * sc); o.y = f2bf(v.y * sc);
    o.z = f2bf(v.z * sc); o.w = f2bf(v.w * sc);
    *(ushort4*)(dst + i) = o;
}

__global__ __launch_bounds__(256) void concat3_kernel(const float* __restrict__ a,
                                                      const float* __restrict__ b,
                                                      const float* __restrict__ c,
                                                      float* __restrict__ o) {
    int i = blockIdx.x * 256 + threadIdx.x;   // 3072 total
    float v = (i < 1024) ? a[i] * QSCALE : ((i < 2048) ? b[i - 1024] : c[i - 2048]);
    o[i] = v;
}

// ---------------------------------------------------------------- layernorm
__global__ __launch_bounds__(256) void ln_kernel(const float* __restrict__ x,
                                                 const float* __restrict__ g,
                                                 const float* __restrict__ bta,
                                                 unsigned short* __restrict__ h) {
    __shared__ float red[8];
    const int row = blockIdx.x;
    const int t = threadIdx.x;
    const float* xr = x + (size_t)row * FEATS;
    float4 v = ((const float4*)xr)[t];
    float s  = v.x + v.y + v.z + v.w;
    float ss = v.x * v.x + v.y * v.y + v.z * v.z + v.w * v.w;
#pragma unroll
    for (int off = 1; off < 64; off <<= 1) {
        s  += __shfl_xor(s, off);
        ss += __shfl_xor(ss, off);
    }
    const int w = t >> 6;
    if ((t & 63) == 0) { red[w] = s; red[4 + w] = ss; }
    __syncthreads();
    s  = red[0] + red[1] + red[2] + red[3];
    ss = red[4] + red[5] + red[6] + red[7];
    const float mu  = s * (1.f / FEATS);
    const float var = ss * (1.f / FEATS) - mu * mu;
    const float rs  = rsqrtf(var + 1e-5f);
    float4 gv = ((const float4*)g)[t];
    float4 bv = ((const float4*)bta)[t];
    ushort4 ov;
    ov.x = f2bf((v.x - mu) * rs * gv.x + bv.x);
    ov.y = f2bf((v.y - mu) * rs * gv.y + bv.y);
    ov.z = f2bf((v.z - mu) * rs * gv.z + bv.z);
    ov.w = f2bf((v.w - mu) * rs * gv.w + bv.w);
    ((ushort4*)h)[(size_t)row * (FEATS / 4) + t] = ov;
}

// ---------------------------------------------------------------- GEMM
// C[M,N] = epilogue(A[M,K] @ W[N,K]^T + bias); 128x128 tile, BK=32.
// Depth-2 pipeline: 3 LDS buffers, counted vmcnt(4), raw s_barrier.
// T2-lite XOR swizzle (both-sides, rule #21): LDS dest linear (gload_lds),
// global source slot pre-permuted slot^(row&3), frag reads use lj^(li&3).
// Takes the 64B-row 8-way bank conflict down to 4-way.
template <bool RELU, bool ADD, bool OUTBF16>
__global__ __launch_bounds__(256, 3)
void gemm_kernel(const unsigned short* __restrict__ A,
                 const unsigned short* __restrict__ W,
                 const float* __restrict__ bias,
                 const float* __restrict__ addend,
                 void* __restrict__ outp,
                 int M, int N, int K, int gx) {
    __shared__ unsigned short lds[3][2][128 * 32];   // [buf][A=0/B=1][row*32+col]

    const int t = threadIdx.x;
    const int w = t >> 6, lane = t & 63;
    const int wr = w >> 1, wc = w & 1;
    const int li = lane & 15, lj = lane >> 4;

    const int nwg = gridDim.x;
    const int cpx = nwg >> 3;
    const int wg = blockIdx.x;
    const int swz = (wg & 7) * cpx + (wg >> 3);
    const int mb = (swz / gx) * 128, nb = (swz % gx) * 128;

    // staging: row srow = lane>>2; global slot pre-swizzled by row&3
    const int srow = lane >> 2;
    const int scg = ((lane & 3) ^ (srow & 3)) * 8;
    const unsigned short* gA = A + (size_t)(mb + w * 16 + srow) * K + scg;
    const unsigned short* gB = W + (size_t)(nb + w * 16 + srow) * K + scg;
    const size_t half = (size_t)64 * K;
    const int lbase = w * 512 + lane * 8;

    // fragment read slot: lj ^ (row&3), row&3 == li&3 for all frag rows
    const int rsw = (lj ^ (li & 3)) * 8;

    const int nt = K >> 5;

#define STAGE(BUF, K0)                                             \
    do {                                                           \
        unsigned short* la_ = &lds[BUF][0][lbase];                 \
        unsigned short* lb_ = &lds[BUF][1][lbase];                 \
        ASYNC16(gA + (K0), la_);                                   \
        ASYNC16(gA + half + (K0), la_ + 2048);                     \
        ASYNC16(gB + (K0), lb_);                                   \
        ASYNC16(gB + half + (K0), lb_ + 2048);                     \
    } while (0)

    STAGE(0, 0);
    STAGE(1, 32);
    asm volatile("s_waitcnt vmcnt(4)" ::: "memory");
    __builtin_amdgcn_s_barrier();

    f32x4 acc[4][4] = {};

    for (int i = 0; i < nt; ++i) {
        const int cur = i % 3;
        const unsigned short* Al = &lds[cur][0][0];
        const unsigned short* Bl = &lds[cur][1][0];

        bf16x8 af[4], bfr[4];
#pragma unroll
        for (int m = 0; m < 4; m++)
            af[m] = *(const bf16x8*)(Al + (wr * 64 + m * 16 + li) * 32 + rsw);
#pragma unroll
        for (int n = 0; n < 4; n++)
            bfr[n] = *(const bf16x8*)(Bl + (wc * 64 + n * 16 + li) * 32 + rsw);

        const int pf = i + 2 < nt;
        if (pf) STAGE((i + 2) % 3, (i + 2) * 32);

#pragma unroll
        for (int m = 0; m < 4; m++)
#pragma unroll
            for (int n = 0; n < 4; n++)
                acc[m][n] = __builtin_amdgcn_mfma_f32_16x16x32_bf16(af[m], bfr[n], acc[m][n], 0, 0, 0);

        if (i + 1 < nt) {
            if (pf) asm volatile("s_waitcnt vmcnt(4)" ::: "memory");
            else    asm volatile("s_waitcnt vmcnt(0)" ::: "memory");
            __builtin_amdgcn_s_barrier();
        }
    }
#undef STAGE

#pragma unroll
    for (int m = 0; m < 4; m++) {
#pragma unroll
        for (int n = 0; n < 4; n++) {
            const int col = nb + wc * 64 + n * 16 + li;
            const float bv = bias[col];
#pragma unroll
            for (int r = 0; r < 4; r++) {
                const int row = mb + wr * 64 + m * 16 + lj * 4 + r;
                float v = acc[m][n][r] + bv;
                if (RELU) v = fmaxf(v, 0.f);
                if (ADD)  v += addend[(size_t)row * N + col];
                if (OUTBF16)
                    ((unsigned short*)outp)[(size_t)row * N + col] = f2bf(v);
                else
                    ((float*)outp)[(size_t)row * N + col] = v;
            }
        }
    }
}

// ---------------------------------------------------------------- V transpose
__global__ __launch_bounds__(256) void vtrans_kernel(const unsigned short* __restrict__ qkv,
                                                     unsigned short* __restrict__ vt) {
    constexpr int LDV = 68;
    __shared__ unsigned short Vl[64 * LDV];
    const int bh = blockIdx.x, st = blockIdx.y;
    const int b = bh >> 4, h = bh & 15;
    const int t = threadIdx.x;
    const unsigned short* src = qkv + (size_t)(b * SEQ + st * 64) * (3 * FEATS) + 2 * FEATS + h * HD;
#pragma unroll
    for (int i = 0; i < 2; i++) {
        int idx = t + i * 256;
        int r = idx >> 3, c = (idx & 7) * 8;
        *(bf16x8*)(Vl + r * LDV + c) = *(const bf16x8*)(src + (size_t)r * (3 * FEATS) + c);
    }
    __syncthreads();
    unsigned short* dst = vt + (size_t)bh * HD * SEQ + st * 64;
#pragma unroll
    for (int i = 0; i < 2; i++) {
        int idx = t + i * 256;
        int d = idx >> 3, s8 = (idx & 7) * 8;
        bf16x8 v;
#pragma unroll
        for (int j = 0; j < 8; j++) v[j] = Vl[(s8 + j) * LDV + d];
        *(bf16x8*)(dst + (size_t)d * SEQ + s8) = v;
    }
}

// ---------------------------------------------------------------- attention
// 512 thr (8 waves x 16 q-rows), KV tile 128. Swapped QK^T keeps P
// lane-local; cvt_pk packs PV A-frags in-register. Q pre-scaled (exp2f(s)
// direct). Grid: bh on x so the 16 q-tile blocks of a head share an XCD L2.
__global__ __launch_bounds__(512, 4)
void attn_kernel(const unsigned short* __restrict__ qkv,
                 const unsigned short* __restrict__ vt,
                 unsigned short* __restrict__ out) {
    constexpr int LK = 72;    // K rows: 64 d + pad (shorts)
    constexpr int LV = 136;   // V^T rows: 128 keys + pad (shorts)
    __shared__ unsigned short Kl[2][128 * LK];
    __shared__ unsigned short Vtl[2][64 * LV];

    const int bh = blockIdx.x;
    const int b = bh >> 4, h = bh & 15;
    const int q0 = blockIdx.y * 128;
    const int t = threadIdx.x, w = t >> 6, lane = t & 63;
    const int li = lane & 15, lj = lane >> 4;

    const size_t rstr = 3 * FEATS;
    const unsigned short* qkvb = qkv + (size_t)(b * SEQ) * rstr;
    const unsigned short* ksrc = qkvb + FEATS + h * HD;
    const unsigned short* vsrc = vt + (size_t)bh * HD * SEQ;

    // Q fragments in registers: B-operand of S^T = K Q^T
    bf16x8 aq[2];
#pragma unroll
    for (int kk = 0; kk < 2; kk++)
        aq[kk] = *(const bf16x8*)(qkvb + (size_t)(q0 + w * 16 + li) * rstr + h * HD + kk * 32 + lj * 8);

    f32x4 o[4] = {};
    float lsum = 0.f;   // denominator for q = li

    // K staging: thread t -> key = t>>2, d-chunk (t&3)*16; two b128
    const int skey = t >> 2, sc = (t & 3) * 16;
    const unsigned short* kg = ksrc + (size_t)skey * rstr + sc;
    const int ldoK = skey * LK + sc;
    // V staging: thread t -> d = t>>3, key-chunk c0 = (t&7)*16; two b128 ->
    // four b64 at permuted slots: pos(k)=(k&96)|(((k>>2)&3)<<3)|(((k>>4)&1)<<2)|(k&3)
    const int sd = t >> 3, c0 = (t & 7) * 16;
    const unsigned short* vg = vsrc + (size_t)sd * SEQ + c0;
    const int posA = (c0 & 96) | (((c0 >> 2) & 3) << 3) | (((c0 >> 4) & 1) << 2);
    const int ldoV = sd * LV + posA;

    const int nt = SEQ / 128;   // 16

#define VSPLIT(VR0, VR1, BUF)                                            \
    do {                                                                 \
        *(bf16x4*)(&Vtl[BUF][ldoV])      = __builtin_shufflevector(VR0, VR0, 0, 1, 2, 3); \
        *(bf16x4*)(&Vtl[BUF][ldoV + 8])  = __builtin_shufflevector(VR0, VR0, 4, 5, 6, 7); \
        *(bf16x4*)(&Vtl[BUF][ldoV + 16]) = __builtin_shufflevector(VR1, VR1, 0, 1, 2, 3); \
        *(bf16x4*)(&Vtl[BUF][ldoV + 24]) = __builtin_shufflevector(VR1, VR1, 4, 5, 6, 7); \
    } while (0)

    // prologue: tile 0 staged
    {
        bf16x8 k0 = *(const bf16x8*)kg;
        bf16x8 k1 = *(const bf16x8*)(kg + 8);
        bf16x8 v0 = *(const bf16x8*)vg;
        bf16x8 v1 = *(const bf16x8*)(vg + 8);
        *(bf16x8*)(&Kl[0][ldoK])     = k0;
        *(bf16x8*)(&Kl[0][ldoK + 8]) = k1;
        VSPLIT(v0, v1, 0);
    }

    int cur = 0;
    for (int i = 0; i < nt; ++i) {
        // issue next tile's global loads early (hidden under this tile's compute)
        bf16x8 kr0, kr1, vr0, vr1;
        if (i + 1 < nt) {
            const unsigned short* kn = kg + (size_t)(i + 1) * 128 * rstr;
            const unsigned short* vn = vg + (i + 1) * 128;
            kr0 = *(const bf16x8*)kn;
            kr1 = *(const bf16x8*)(kn + 8);
            vr0 = *(const bf16x8*)vn;
            vr1 = *(const bf16x8*)(vn + 8);
        }

        // barrier: LDS writes of buf[cur] visible; global loads stay in flight
        asm volatile("s_waitcnt lgkmcnt(0)" ::: "memory");
        __builtin_amdgcn_s_barrier();

        const unsigned short* Kc = Kl[cur];
        const unsigned short* Vc = Vtl[cur];

        // ---- S^T = K Q^T : lane holds S[q=li][key = n*16 + lj*4 + r] ----
        f32x4 s[8];
        __builtin_amdgcn_s_setprio(1);
#pragma unroll
        for (int n = 0; n < 8; n++) {
            bf16x8 k0 = *(const bf16x8*)(Kc + (n * 16 + li) * LK + lj * 8);
            bf16x8 k1 = *(const bf16x8*)(Kc + (n * 16 + li) * LK + 32 + lj * 8);
            f32x4 acc = {};
            acc = __builtin_amdgcn_mfma_f32_16x16x32_bf16(k0, aq[0], acc, 0, 0, 0);
            acc = __builtin_amdgcn_mfma_f32_16x16x32_bf16(k1, aq[1], acc, 0, 0, 0);
            s[n] = acc;
        }
        __builtin_amdgcn_s_setprio(0);

        // ---- p = exp2(s) (pre-scaled); pack PV A-frags in-register ----
        bf16x8 A[4];
#pragma unroll
        for (int kk = 0; kk < 4; kk++) {
            float p[8];
#pragma unroll
            for (int r = 0; r < 4; r++) {
                p[r]     = exp2f(s[2 * kk][r]);
                p[4 + r] = exp2f(s[2 * kk + 1][r]);
                lsum += p[r] + p[4 + r];
            }
            union { unsigned u[4]; bf16x8 v; } Au;
            asm("v_cvt_pk_bf16_f32 %0, %1, %2" : "=v"(Au.u[0]) : "v"(p[0]), "v"(p[1]));
            asm("v_cvt_pk_bf16_f32 %0, %1, %2" : "=v"(Au.u[1]) : "v"(p[2]), "v"(p[3]));
            asm("v_cvt_pk_bf16_f32 %0, %1, %2" : "=v"(Au.u[2]) : "v"(p[4]), "v"(p[5]));
            asm("v_cvt_pk_bf16_f32 %0, %1, %2" : "=v"(Au.u[3]) : "v"(p[6]), "v"(p[7]));
            A[kk] = Au.v;
        }

        // ---- O += P V (V^T rows key-slot-permuted to match A) ----
        __builtin_amdgcn_s_setprio(1);
#pragma unroll
        for (int n = 0; n < 4; n++) {
#pragma unroll
            for (int kk = 0; kk < 4; kk++) {
                bf16x8 bv = *(const bf16x8*)(Vc + (n * 16 + li) * LV + kk * 32 + lj * 8);
                o[n] = __builtin_amdgcn_mfma_f32_16x16x32_bf16(A[kk], bv, o[n], 0, 0, 0);
            }
        }
        __builtin_amdgcn_s_setprio(0);

        // write-late: prefetched tile into the other buffer
        if (i + 1 < nt) {
            *(bf16x8*)(&Kl[cur ^ 1][ldoK])     = kr0;
            *(bf16x8*)(&Kl[cur ^ 1][ldoK + 8]) = kr1;
            VSPLIT(vr0, vr1, cur ^ 1);
        }
        cur ^= 1;
    }
#undef VSPLIT

    // denominator: full sum for q = li lives across lj groups
    lsum += __shfl_xor(lsum, 16);
    lsum += __shfl_xor(lsum, 32);
    const float dinv = 1.f / lsum;
    // epilogue rows are q' = lj*4 + r -> fetch that q's inv via lane shuffle
    float inv[4];
#pragma unroll
    for (int r = 0; r < 4; r++)
        inv[r] = __shfl(dinv, lj * 4 + r);

    unsigned short* ob = out + (size_t)(b * SEQ + q0 + w * 16) * FEATS + h * HD;
#pragma unroll
    for (int n = 0; n < 4; n++)
#pragma unroll
        for (int r = 0; r < 4; r++)
            ob[(size_t)(lj * 4 + r) * FEATS + n * 16 + li] = f2bf(o[n][r] * inv[r]);
}

// ---------------------------------------------------------------- launch
extern "C" void kernel_launch(void* const* d_in, const int* in_sizes, int n_in,
                              void* d_out, int out_size, void* d_ws, size_t ws_size,
                              hipStream_t stream) {
    const float* x     = (const float*)d_in[0];
    const float* ln1_g = (const float*)d_in[1];
    const float* ln1_b = (const float*)d_in[2];
    const float* wq    = (const float*)d_in[3];
    const float* bq    = (const float*)d_in[4];
    const float* wk    = (const float*)d_in[5];
    const float* bk    = (const float*)d_in[6];
    const float* wv    = (const float*)d_in[7];
    const float* bvv   = (const float*)d_in[8];
    const float* wo    = (const float*)d_in[9];
    const float* bo    = (const float*)d_in[10];
    const float* ln2_g = (const float*)d_in[11];
    const float* ln2_b = (const float*)d_in[12];
    const float* w1    = (const float*)d_in[13];
    const float* b1    = (const float*)d_in[14];
    const float* w2    = (const float*)d_in[15];
    const float* b2    = (const float*)d_in[16];

    // ---- workspace layout (~84 MB) ----
    unsigned short* wqkv_b = (unsigned short*)d_ws;                 // 3072*1024
    unsigned short* wo_b   = wqkv_b + 3072 * 1024;                  // 1024*1024
    unsigned short* w1_b   = wo_b + 1024 * 1024;                    // 4096*1024
    unsigned short* w2_b   = w1_b + 4096 * 1024;                    // 1024*4096
    float*          bqkv   = (float*)(w2_b + 1024 * 4096);          // 3072
    unsigned short* region = (unsigned short*)(bqkv + 3072);
    unsigned short* qkvb   = region;                                // 4096*3072
    unsigned short* hb     = region + (size_t)4096 * 3072;          // 4096*1024 (LN1 out)
    unsigned short* vtb    = hb;                                    // 32*64*2048 (hb dead after QKV gemm)
    unsigned short* a1     = region;                                // 4096*4096 (qkv+vt dead after attn)
    unsigned short* attn_o = region + (size_t)4096 * 4096;          // 4096*1024
    unsigned short* h2     = attn_o;                                // alias (attn_o dead when written)
    float*          out1   = (float*)(attn_o + (size_t)4096 * 1024);// 4096*1024 fp32
    float*          outf   = (float*)d_out;

    dim3 blk(256);

    // all weight converts in one launch (12M elements, dests contiguous)
    cvt_all_kernel<<<12288, blk, 0, stream>>>(wq, wk, wv, wo, w1, w2, wqkv_b);
    concat3_kernel<<<12, blk, 0, stream>>>(bq, bk, bvv, bqkv);

    ln_kernel<<<MTOT, blk, 0, stream>>>(x, ln1_g, ln1_b, hb);

    // fused QKV gemm: (4096,1024) @ (3072,1024)^T ; grid 24x32 = 768 blocks
    gemm_kernel<false, false, true><<<768, blk, 0, stream>>>(
        hb, wqkv_b, bqkv, nullptr, qkvb, MTOT, 3072, FEATS, 24);

    vtrans_kernel<<<dim3(BATCH * NH, SEQ / 64), blk, 0, stream>>>(qkvb, vtb);

    attn_kernel<<<dim3(BATCH * NH, SEQ / 128), dim3(512), 0, stream>>>(qkvb, vtb, attn_o);

    // out proj + residual: grid 8x32 = 256 blocks
    gemm_kernel<false, true, false><<<256, blk, 0, stream>>>(
        attn_o, wo_b, bo, x, out1, MTOT, FEATS, FEATS, 8);

    ln_kernel<<<MTOT, blk, 0, stream>>>(out1, ln2_g, ln2_b, h2);

    // MLP1: grid 32x32 = 1024 blocks
    gemm_kernel<true, false, true><<<1024, blk, 0, stream>>>(
        h2, w1_b, b1, nullptr, a1, MTOT, MLPH, FEATS, 32);

    // MLP2: grid 8x32 = 256 blocks
    gemm_kernel<true, true, false><<<256, blk, 0, stream>>>(
        a1, w2_b, b2, out1, outf, MTOT, FEATS, MLPH, 8);
}

// Round 10
// 232.676 us; speedup vs baseline: 1.1127x; 1.0141x over previous
//
#include <hip/hip_runtime.h>
#include <hip/hip_bf16.h>

#define FEATS 1024
#define NH 16
#define HD 64
#define SEQ 2048
#define BATCH 2
#define MTOT (BATCH*SEQ)   // 4096
#define MLPH 4096
// log2(e)/sqrt(FEATS): folded into wq/bq so attn uses exp2f(s) directly
#define QSCALE 0.04508422277369218f

typedef __attribute__((ext_vector_type(8))) short bf16x8;   // 8 bf16 (4 VGPRs)
typedef __attribute__((ext_vector_type(4))) short bf16x4;   // 4 bf16 (2 VGPRs)
typedef __attribute__((ext_vector_type(4))) float f32x4;

static_assert(sizeof(bf16x8) == 16, "bf16x8 must be 16B");

__device__ __forceinline__ unsigned short f2bf(float f) {
    unsigned int u = __float_as_uint(f);
    unsigned int lsb = (u >> 16) & 1u;
    u += 0x7fffu + lsb;              // round-to-nearest-even
    return (unsigned short)(u >> 16);
}

// async global->LDS, 16B per lane. Dest must be wave-uniform base + lane*16.
#define ASYNC16(GP, LP) __builtin_amdgcn_global_load_lds( \
    (const __attribute__((address_space(1))) void*)(GP),  \
    (__attribute__((address_space(3))) void*)(LP), 16, 0, 0)

// ---------------------------------------------------------------- converts
// single launch for all 6 weight matrices (dests are contiguous in ws)
__global__ __launch_bounds__(256) void cvt_all_kernel(
    const float* __restrict__ wq, const float* __restrict__ wk,
    const float* __restrict__ wv, const float* __restrict__ wo,
    const float* __restrict__ w1, const float* __restrict__ w2,
    unsigned short* __restrict__ dst) {
    const size_t i = ((size_t)blockIdx.x * 256 + threadIdx.x) * 4;
    const size_t MB = (size_t)1024 * 1024;
    const float* s;
    size_t off;
    float sc = 1.0f;
    if (i < MB)            { s = wq; off = i;          sc = QSCALE; }
    else if (i < 2 * MB)   { s = wk; off = i - MB; }
    else if (i < 3 * MB)   { s = wv; off = i - 2 * MB; }
    else if (i < 4 * MB)   { s = wo; off = i - 3 * MB; }
    else if (i < 8 * MB)   { s = w1; off = i - 4 * MB; }
    else                   { s = w2; off = i - 8 * MB; }
    float4 v = *(const float4*)(s + off);
    ushort4 o;
    o.x = f2bf(v.x * sc); o.y = f2bf(v.y * sc);
    o.z = f2bf(v.z * sc); o.w = f2bf(v.w * sc);
    *(ushort4*)(dst + i) = o;
}

__global__ __launch_bounds__(256) void concat3_kernel(const float* __restrict__ a,
                                                      const float* __restrict__ b,
                                                      const float* __restrict__ c,
                                                      float* __restrict__ o) {
    int i = blockIdx.x * 256 + threadIdx.x;   // 3072 total
    float v = (i < 1024) ? a[i] * QSCALE : ((i < 2048) ? b[i - 1024] : c[i - 2048]);
    o[i] = v;
}

// ---------------------------------------------------------------- layernorm
__global__ __launch_bounds__(256) void ln_kernel(const float* __restrict__ x,
                                                 const float* __restrict__ g,
                                                 const float* __restrict__ bta,
                                                 unsigned short* __restrict__ h) {
    __shared__ float red[8];
    const int row = blockIdx.x;
    const int t = threadIdx.x;
    const float* xr = x + (size_t)row * FEATS;
    float4 v = ((const float4*)xr)[t];
    float s  = v.x + v.y + v.z + v.w;
    float ss = v.x * v.x + v.y * v.y + v.z * v.z + v.w * v.w;
#pragma unroll
    for (int off = 1; off < 64; off <<= 1) {
        s  += __shfl_xor(s, off);
        ss += __shfl_xor(ss, off);
    }
    const int w = t >> 6;
    if ((t & 63) == 0) { red[w] = s; red[4 + w] = ss; }
    __syncthreads();
    s  = red[0] + red[1] + red[2] + red[3];
    ss = red[4] + red[5] + red[6] + red[7];
    const float mu  = s * (1.f / FEATS);
    const float var = ss * (1.f / FEATS) - mu * mu;
    const float rs  = rsqrtf(var + 1e-5f);
    float4 gv = ((const float4*)g)[t];
    float4 bv = ((const float4*)bta)[t];
    ushort4 ov;
    ov.x = f2bf((v.x - mu) * rs * gv.x + bv.x);
    ov.y = f2bf((v.y - mu) * rs * gv.y + bv.y);
    ov.z = f2bf((v.z - mu) * rs * gv.z + bv.z);
    ov.w = f2bf((v.w - mu) * rs * gv.w + bv.w);
    ((ushort4*)h)[(size_t)row * (FEATS / 4) + t] = ov;
}

// ---------------------------------------------------------------- GEMM
// C[M,N] = epilogue(A[M,K] @ W[N,K]^T + bias); 128x128 tile, BK=32.
// Depth-2 pipeline: 3 LDS buffers, counted vmcnt(4), raw s_barrier.
// T2-lite XOR swizzle (both-sides): 8-way -> 4-way bank conflict.
template <bool RELU, bool ADD, bool OUTBF16>
__global__ __launch_bounds__(256, 3)
void gemm_kernel(const unsigned short* __restrict__ A,
                 const unsigned short* __restrict__ W,
                 const float* __restrict__ bias,
                 const float* __restrict__ addend,
                 void* __restrict__ outp,
                 int M, int N, int K, int gx) {
    __shared__ unsigned short lds[3][2][128 * 32];   // [buf][A=0/B=1][row*32+col]

    const int t = threadIdx.x;
    const int w = t >> 6, lane = t & 63;
    const int wr = w >> 1, wc = w & 1;
    const int li = lane & 15, lj = lane >> 4;

    const int nwg = gridDim.x;
    const int cpx = nwg >> 3;
    const int wg = blockIdx.x;
    const int swz = (wg & 7) * cpx + (wg >> 3);
    const int mb = (swz / gx) * 128, nb = (swz % gx) * 128;

    // staging: row srow = lane>>2; global slot pre-swizzled by row&3
    const int srow = lane >> 2;
    const int scg = ((lane & 3) ^ (srow & 3)) * 8;
    const unsigned short* gA = A + (size_t)(mb + w * 16 + srow) * K + scg;
    const unsigned short* gB = W + (size_t)(nb + w * 16 + srow) * K + scg;
    const size_t half = (size_t)64 * K;
    const int lbase = w * 512 + lane * 8;

    // fragment read slot: lj ^ (row&3), row&3 == li&3 for all frag rows
    const int rsw = (lj ^ (li & 3)) * 8;

    const int nt = K >> 5;

#define STAGE(BUF, K0)                                             \
    do {                                                           \
        unsigned short* la_ = &lds[BUF][0][lbase];                 \
        unsigned short* lb_ = &lds[BUF][1][lbase];                 \
        ASYNC16(gA + (K0), la_);                                   \
        ASYNC16(gA + half + (K0), la_ + 2048);                     \
        ASYNC16(gB + (K0), lb_);                                   \
        ASYNC16(gB + half + (K0), lb_ + 2048);                     \
    } while (0)

    STAGE(0, 0);
    STAGE(1, 32);
    asm volatile("s_waitcnt vmcnt(4)" ::: "memory");
    __builtin_amdgcn_s_barrier();

    f32x4 acc[4][4] = {};

    for (int i = 0; i < nt; ++i) {
        const int cur = i % 3;
        const unsigned short* Al = &lds[cur][0][0];
        const unsigned short* Bl = &lds[cur][1][0];

        bf16x8 af[4], bfr[4];
#pragma unroll
        for (int m = 0; m < 4; m++)
            af[m] = *(const bf16x8*)(Al + (wr * 64 + m * 16 + li) * 32 + rsw);
#pragma unroll
        for (int n = 0; n < 4; n++)
            bfr[n] = *(const bf16x8*)(Bl + (wc * 64 + n * 16 + li) * 32 + rsw);

        const int pf = i + 2 < nt;
        if (pf) STAGE((i + 2) % 3, (i + 2) * 32);

#pragma unroll
        for (int m = 0; m < 4; m++)
#pragma unroll
            for (int n = 0; n < 4; n++)
                acc[m][n] = __builtin_amdgcn_mfma_f32_16x16x32_bf16(af[m], bfr[n], acc[m][n], 0, 0, 0);

        if (i + 1 < nt) {
            if (pf) asm volatile("s_waitcnt vmcnt(4)" ::: "memory");
            else    asm volatile("s_waitcnt vmcnt(0)" ::: "memory");
            __builtin_amdgcn_s_barrier();
        }
    }
#undef STAGE

#pragma unroll
    for (int m = 0; m < 4; m++) {
#pragma unroll
        for (int n = 0; n < 4; n++) {
            const int col = nb + wc * 64 + n * 16 + li;
            const float bv = bias[col];
#pragma unroll
            for (int r = 0; r < 4; r++) {
                const int row = mb + wr * 64 + m * 16 + lj * 4 + r;
                float v = acc[m][n][r] + bv;
                if (RELU) v = fmaxf(v, 0.f);
                if (ADD)  v += addend[(size_t)row * N + col];
                if (OUTBF16)
                    ((unsigned short*)outp)[(size_t)row * N + col] = f2bf(v);
                else
                    ((float*)outp)[(size_t)row * N + col] = v;
            }
        }
    }
}

// ---------------------------------------------------------------- V transpose
__global__ __launch_bounds__(256) void vtrans_kernel(const unsigned short* __restrict__ qkv,
                                                     unsigned short* __restrict__ vt) {
    constexpr int LDV = 68;
    __shared__ unsigned short Vl[64 * LDV];
    const int bh = blockIdx.x, st = blockIdx.y;
    const int b = bh >> 4, h = bh & 15;
    const int t = threadIdx.x;
    const unsigned short* src = qkv + (size_t)(b * SEQ + st * 64) * (3 * FEATS) + 2 * FEATS + h * HD;
#pragma unroll
    for (int i = 0; i < 2; i++) {
        int idx = t + i * 256;
        int r = idx >> 3, c = (idx & 7) * 8;
        *(bf16x8*)(Vl + r * LDV + c) = *(const bf16x8*)(src + (size_t)r * (3 * FEATS) + c);
    }
    __syncthreads();
    unsigned short* dst = vt + (size_t)bh * HD * SEQ + st * 64;
#pragma unroll
    for (int i = 0; i < 2; i++) {
        int idx = t + i * 256;
        int d = idx >> 3, s8 = (idx & 7) * 8;
        bf16x8 v;
#pragma unroll
        for (int j = 0; j < 8; j++) v[j] = Vl[(s8 + j) * LDV + d];
        *(bf16x8*)(dst + (size_t)d * SEQ + s8) = v;
    }
}

// ---------------------------------------------------------------- attention
// 256 thr (4 waves x 32 q-rows = two 16-row halves), KV tile 128.
// Fatter waves: each K/V LDS fragment read feeds BOTH q-halves -> LDS read
// traffic per FLOP halved vs 16q/wave. Swapped QK^T keeps P lane-local;
// cvt_pk packs PV A-frags in-register; denominator via ones-MFMA (B-operand
// is a constant register) -> no lsum adds, no epilogue shuffles.
__global__ __launch_bounds__(256, 2)
void attn_kernel(const unsigned short* __restrict__ qkv,
                 const unsigned short* __restrict__ vt,
                 unsigned short* __restrict__ out) {
    constexpr int LK = 72;    // K rows: 64 d + pad (shorts)
    constexpr int LV = 136;   // V^T rows: 128 keys + pad (shorts)
    __shared__ unsigned short Kl[2][128 * LK];
    __shared__ unsigned short Vtl[2][64 * LV];

    const int bh = blockIdx.x;
    const int b = bh >> 4, h = bh & 15;
    const int q0 = blockIdx.y * 128;
    const int t = threadIdx.x, w = t >> 6, lane = t & 63;
    const int li = lane & 15, lj = lane >> 4;

    const size_t rstr = 3 * FEATS;
    const unsigned short* qkvb = qkv + (size_t)(b * SEQ) * rstr;
    const unsigned short* ksrc = qkvb + FEATS + h * HD;
    const unsigned short* vsrc = vt + (size_t)bh * HD * SEQ;

    // Q fragments: two 16-row halves per wave
    bf16x8 aq[2][2];
#pragma unroll
    for (int hh = 0; hh < 2; hh++)
#pragma unroll
        for (int kk = 0; kk < 2; kk++)
            aq[hh][kk] = *(const bf16x8*)(qkvb +
                (size_t)(q0 + w * 32 + hh * 16 + li) * rstr + h * HD + kk * 32 + lj * 8);

    f32x4 o[2][4] = {};
    f32x4 oS[2] = {};   // denominators (ones-MFMA accumulator)

    const short onebf = (short)0x3F80;   // bf16 1.0
    const bf16x8 ones = {onebf, onebf, onebf, onebf, onebf, onebf, onebf, onebf};

    // K staging: thread t -> key = t>>1 (0..127), d-chunk (t&1)*32 (4 b128)
    const int skey = t >> 1, dbase = (t & 1) * 32;
    const unsigned short* kg = ksrc + (size_t)skey * rstr + dbase;
    const int ldoK = skey * LK + dbase;
    // V staging: thread t -> d = t>>2 (0..63), keys (t&3)*32..+31 (4 groups of 8)
    // group u at key c=kbase+8u -> permuted pos kbase + (u&1)*16 + (u>>1)*4
    const int sd = t >> 2, kbase = (t & 3) * 32;
    const unsigned short* vg = vsrc + (size_t)sd * SEQ + kbase;
    const int ldoV = sd * LV + kbase;

    const int nt = SEQ / 128;   // 16

#define KW(BUF, R0, R1, R2, R3)                          \
    do {                                                 \
        *(bf16x8*)(&Kl[BUF][ldoK])      = R0;            \
        *(bf16x8*)(&Kl[BUF][ldoK + 8])  = R1;            \
        *(bf16x8*)(&Kl[BUF][ldoK + 16]) = R2;            \
        *(bf16x8*)(&Kl[BUF][ldoK + 24]) = R3;            \
    } while (0)
#define VW1(BUF, VR, POS)                                                              \
    do {                                                                               \
        *(bf16x4*)(&Vtl[BUF][(POS)])     = __builtin_shufflevector(VR, VR, 0, 1, 2, 3);\
        *(bf16x4*)(&Vtl[BUF][(POS) + 8]) = __builtin_shufflevector(VR, VR, 4, 5, 6, 7);\
    } while (0)
#define VW(BUF, V0, V1, V2, V3)                          \
    do {                                                 \
        VW1(BUF, V0, ldoV);                              \
        VW1(BUF, V1, ldoV + 16);                         \
        VW1(BUF, V2, ldoV + 4);                          \
        VW1(BUF, V3, ldoV + 20);                         \
    } while (0)

    // prologue: tile 0 staged
    {
        bf16x8 k0 = *(const bf16x8*)kg;
        bf16x8 k1 = *(const bf16x8*)(kg + 8);
        bf16x8 k2 = *(const bf16x8*)(kg + 16);
        bf16x8 k3 = *(const bf16x8*)(kg + 24);
        bf16x8 v0 = *(const bf16x8*)vg;
        bf16x8 v1 = *(const bf16x8*)(vg + 8);
        bf16x8 v2 = *(const bf16x8*)(vg + 16);
        bf16x8 v3 = *(const bf16x8*)(vg + 24);
        KW(0, k0, k1, k2, k3);
        VW(0, v0, v1, v2, v3);
    }

    int cur = 0;
    for (int i = 0; i < nt; ++i) {
        // issue next tile's global loads early (hidden under this tile's compute)
        bf16x8 kr0, kr1, kr2, kr3, vr0, vr1, vr2, vr3;
        if (i + 1 < nt) {
            const unsigned short* kn = kg + (size_t)(i + 1) * 128 * rstr;
            const unsigned short* vn = vg + (i + 1) * 128;
            kr0 = *(const bf16x8*)kn;
            kr1 = *(const bf16x8*)(kn + 8);
            kr2 = *(const bf16x8*)(kn + 16);
            kr3 = *(const bf16x8*)(kn + 24);
            vr0 = *(const bf16x8*)vn;
            vr1 = *(const bf16x8*)(vn + 8);
            vr2 = *(const bf16x8*)(vn + 16);
            vr3 = *(const bf16x8*)(vn + 24);
        }

        // barrier: LDS writes of buf[cur] visible; global loads stay in flight
        asm volatile("s_waitcnt lgkmcnt(0)" ::: "memory");
        __builtin_amdgcn_s_barrier();

        const unsigned short* Kc = Kl[cur];
        const unsigned short* Vc = Vtl[cur];

        // ---- S^T = K Q^T : both q-halves share each K fragment ----
        f32x4 s[2][8];
        __builtin_amdgcn_s_setprio(1);
#pragma unroll
        for (int n = 0; n < 8; n++) {
            bf16x8 k0 = *(const bf16x8*)(Kc + (n * 16 + li) * LK + lj * 8);
            bf16x8 k1 = *(const bf16x8*)(Kc + (n * 16 + li) * LK + 32 + lj * 8);
#pragma unroll
            for (int hh = 0; hh < 2; hh++) {
                f32x4 acc = {};
                acc = __builtin_amdgcn_mfma_f32_16x16x32_bf16(k0, aq[hh][0], acc, 0, 0, 0);
                acc = __builtin_amdgcn_mfma_f32_16x16x32_bf16(k1, aq[hh][1], acc, 0, 0, 0);
                s[hh][n] = acc;
            }
        }
        __builtin_amdgcn_s_setprio(0);

        // ---- p = exp2(s) (pre-scaled); pack PV A-frags in-register ----
        bf16x8 A[2][4];
#pragma unroll
        for (int hh = 0; hh < 2; hh++)
#pragma unroll
            for (int kk = 0; kk < 4; kk++) {
                float p[8];
#pragma unroll
                for (int r = 0; r < 4; r++) {
                    p[r]     = exp2f(s[hh][2 * kk][r]);
                    p[4 + r] = exp2f(s[hh][2 * kk + 1][r]);
                }
                union { unsigned u[4]; bf16x8 v; } Au;
                asm("v_cvt_pk_bf16_f32 %0, %1, %2" : "=v"(Au.u[0]) : "v"(p[0]), "v"(p[1]));
                asm("v_cvt_pk_bf16_f32 %0, %1, %2" : "=v"(Au.u[1]) : "v"(p[2]), "v"(p[3]));
                asm("v_cvt_pk_bf16_f32 %0, %1, %2" : "=v"(Au.u[2]) : "v"(p[4]), "v"(p[5]));
                asm("v_cvt_pk_bf16_f32 %0, %1, %2" : "=v"(Au.u[3]) : "v"(p[6]), "v"(p[7]));
                A[hh][kk] = Au.v;
            }

        // ---- denominators: oS += A * ones (register B-operand) ----
#pragma unroll
        for (int hh = 0; hh < 2; hh++)
#pragma unroll
            for (int kk = 0; kk < 4; kk++)
                oS[hh] = __builtin_amdgcn_mfma_f32_16x16x32_bf16(A[hh][kk], ones, oS[hh], 0, 0, 0);

        // ---- O += P V (V^T key-slot-permuted; each V frag feeds both halves) ----
        __builtin_amdgcn_s_setprio(1);
#pragma unroll
        for (int n = 0; n < 4; n++) {
#pragma unroll
            for (int kk = 0; kk < 4; kk++) {
                bf16x8 bv = *(const bf16x8*)(Vc + (n * 16 + li) * LV + kk * 32 + lj * 8);
                o[0][n] = __builtin_amdgcn_mfma_f32_16x16x32_bf16(A[0][kk], bv, o[0][n], 0, 0, 0);
                o[1][n] = __builtin_amdgcn_mfma_f32_16x16x32_bf16(A[1][kk], bv, o[1][n], 0, 0, 0);
            }
        }
        __builtin_amdgcn_s_setprio(0);

        // write-late: prefetched tile into the other buffer
        if (i + 1 < nt) {
            KW(cur ^ 1, kr0, kr1, kr2, kr3);
            VW(cur ^ 1, vr0, vr1, vr2, vr3);
        }
        cur ^= 1;
    }
#undef KW
#undef VW
#undef VW1

    // epilogue: oS[hh][r] is the full denominator for q-row hh*16 + lj*4 + r
    unsigned short* ob = out + (size_t)(b * SEQ + q0 + w * 32) * FEATS + h * HD;
#pragma unroll
    for (int hh = 0; hh < 2; hh++)
#pragma unroll
        for (int r = 0; r < 4; r++) {
            const float inv = 1.f / oS[hh][r];
#pragma unroll
            for (int n = 0; n < 4; n++)
                ob[(size_t)(hh * 16 + lj * 4 + r) * FEATS + n * 16 + li] =
                    f2bf(o[hh][n][r] * inv);
        }
}

// ---------------------------------------------------------------- launch
extern "C" void kernel_launch(void* const* d_in, const int* in_sizes, int n_in,
                              void* d_out, int out_size, void* d_ws, size_t ws_size,
                              hipStream_t stream) {
    const float* x     = (const float*)d_in[0];
    const float* ln1_g = (const float*)d_in[1];
    const float* ln1_b = (const float*)d_in[2];
    const float* wq    = (const float*)d_in[3];
    const float* bq    = (const float*)d_in[4];
    const float* wk    = (const float*)d_in[5];
    const float* bk    = (const float*)d_in[6];
    const float* wv    = (const float*)d_in[7];
    const float* bvv   = (const float*)d_in[8];
    const float* wo    = (const float*)d_in[9];
    const float* bo    = (const float*)d_in[10];
    const float* ln2_g = (const float*)d_in[11];
    const float* ln2_b = (const float*)d_in[12];
    const float* w1    = (const float*)d_in[13];
    const float* b1    = (const float*)d_in[14];
    const float* w2    = (const float*)d_in[15];
    const float* b2    = (const float*)d_in[16];

    // ---- workspace layout (~84 MB) ----
    unsigned short* wqkv_b = (unsigned short*)d_ws;                 // 3072*1024
    unsigned short* wo_b   = wqkv_b + 3072 * 1024;                  // 1024*1024
    unsigned short* w1_b   = wo_b + 1024 * 1024;                    // 4096*1024
    unsigned short* w2_b   = w1_b + 4096 * 1024;                    // 1024*4096
    float*          bqkv   = (float*)(w2_b + 1024 * 4096);          // 3072
    unsigned short* region = (unsigned short*)(bqkv + 3072);
    unsigned short* qkvb   = region;                                // 4096*3072
    unsigned short* hb     = region + (size_t)4096 * 3072;          // 4096*1024 (LN1 out)
    unsigned short* vtb    = hb;                                    // 32*64*2048 (hb dead after QKV gemm)
    unsigned short* a1     = region;                                // 4096*4096 (qkv+vt dead after attn)
    unsigned short* attn_o = region + (size_t)4096 * 4096;          // 4096*1024
    unsigned short* h2     = attn_o;                                // alias (attn_o dead when written)
    float*          out1   = (float*)(attn_o + (size_t)4096 * 1024);// 4096*1024 fp32
    float*          outf   = (float*)d_out;

    dim3 blk(256);

    // all weight converts in one launch (12M elements, dests contiguous)
    cvt_all_kernel<<<12288, blk, 0, stream>>>(wq, wk, wv, wo, w1, w2, wqkv_b);
    concat3_kernel<<<12, blk, 0, stream>>>(bq, bk, bvv, bqkv);

    ln_kernel<<<MTOT, blk, 0, stream>>>(x, ln1_g, ln1_b, hb);

    // fused QKV gemm: (4096,1024) @ (3072,1024)^T ; grid 24x32 = 768 blocks
    gemm_kernel<false, false, true><<<768, blk, 0, stream>>>(
        hb, wqkv_b, bqkv, nullptr, qkvb, MTOT, 3072, FEATS, 24);

    vtrans_kernel<<<dim3(BATCH * NH, SEQ / 64), blk, 0, stream>>>(qkvb, vtb);

    attn_kernel<<<dim3(BATCH * NH, SEQ / 128), dim3(256), 0, stream>>>(qkvb, vtb, attn_o);

    // out proj + residual: grid 8x32 = 256 blocks
    gemm_kernel<false, true, false><<<256, blk, 0, stream>>>(
        attn_o, wo_b, bo, x, out1, MTOT, FEATS, FEATS, 8);

    ln_kernel<<<MTOT, blk, 0, stream>>>(out1, ln2_g, ln2_b, h2);

    // MLP1: grid 32x32 = 1024 blocks
    gemm_kernel<true, false, true><<<1024, blk, 0, stream>>>(
        h2, w1_b, b1, nullptr, a1, MTOT, MLPH, FEATS, 32);

    // MLP2: grid 8x32 = 256 blocks
    gemm_kernel<true, true, false><<<256, blk, 0, stream>>>(
        a1, w2_b, b2, out1, outf, MTOT, FEATS, MLPH, 8);
}